// Round 4
// baseline (194.467 us; speedup 1.0000x reference)
//
#include <hip/hip_runtime.h>
#include <hip/hip_cooperative_groups.h>
#include <stdint.h>

namespace cg = cooperative_groups;

#define NE 8
#define ND 512
#define NH1 512
#define NH2 256
#define NY 256
#define NB 8192
#define BM3 48                   /* fused-tile rows: <=178 tiles, one round on 256 CUs */
#define NBLK 192                 /* cooperative grid; >= worst-case 178 tiles, <=256 CUs */
/* 64x64 transpose tiles */
#define W1T64 (NE * (ND/64) * (NH1/64))   /* 512 */
#define W2T64 (NE * (NH1/64) * (NH2/64))  /* 256 */
#define W3T64 (NE * (NH2/64) * (NY/64))   /* 128 */
#define WTT64 (W1T64 + W2T64 + W3T64)     /* 896 */
#define NUNIT (WTT64 + 1)                 /* 897: transposes + sort */

typedef float f32x4 __attribute__((ext_vector_type(4)));
typedef __bf16 bf16x8 __attribute__((ext_vector_type(8)));
typedef unsigned short u16x8 __attribute__((ext_vector_type(8)));

__device__ __forceinline__ unsigned short f2bf(float f) {
  unsigned int u = __float_as_uint(f);
  u += 0x7fffu + ((u >> 16) & 1u);   // round-to-nearest-even
  return (unsigned short)(u >> 16);
}

__device__ __forceinline__ int clampe(int g) {
  return g < 0 ? 0 : (g > NE - 1 ? NE - 1 : g);
}

// Fragment-order W layout: element (k = kt*32 + (lane>>4)*8 + j, n = f*16 + (lane&15))
// lives at Wf[(((kt * (N/16)) + f) * 64 + lane) * 8 + j]. One wave-load of frag
// (kt,f) = 64 lanes x 16B = 1KB fully contiguous.
//
// Single cooperative kernel (R4): phase 1 = W transpose (897 units over 192
// blocks, 512 thr/unit) + counting sort (unit 896); threadfence + grid.sync();
// phase 2 = R3's fused 3-layer MLP per 48-row tile, tile chosen by a
// deterministic prefix scan over per-expert tile counts (no atomics).
// Merging removes one dispatch (~3-4us gap) and the prep->mlp pipeline drain.
//
// meta ints: [0..7] counts, [8..15] offs, [16..23] ntiles

__global__ __launch_bounds__(512, 4)
void moe_k(const float* __restrict__ h, const int* __restrict__ gate,
           const float* __restrict__ W1, const float* __restrict__ W2,
           const float* __restrict__ W3,
           const float* __restrict__ b1, const float* __restrict__ b2,
           const float* __restrict__ b3,
           float* __restrict__ out,
           int* __restrict__ meta, int* __restrict__ perm,
           unsigned short* __restrict__ w1f, unsigned short* __restrict__ w2f,
           unsigned short* __restrict__ w3f)
{
  __shared__ char smem[100032] __attribute__((aligned(16)));
  // phase-2 carve
  unsigned short* sA = (unsigned short*)smem;            // [48][520] h-tile; a2 overlays (stride 264)
  unsigned short* sB = sA + BM3 * 520;                   // [48][520] a1
  int* permc = (int*)(smem + 99840);                     // [48]

  int bid = blockIdx.x, tid = threadIdx.x;

  // ================= phase 1: W transpose + sort =================
  for (int ui = 0; ui < 5; ui++) {
    int u = bid + ui * NBLK;
    if (u >= NUNIT) break;

    if (u < WTT64) {
      // ---- 64x64 transpose tile, 512 threads ----
      float* ldsf = (float*)smem;   // [64][65]
      const float* src; unsigned short* dst; int K, N, idx;
      if (u < W1T64)              { src = W1; dst = w1f; K = ND;  N = NH1; idx = u; }
      else if (u < W1T64 + W2T64) { src = W2; dst = w2f; K = NH1; N = NH2; idx = u - W1T64; }
      else                        { src = W3; dst = w3f; K = NH2; N = NY;  idx = u - W1T64 - W2T64; }
      int ntn = N >> 6, ntk = K >> 6;
      int n0 = (idx % ntn) * 64;
      int k0 = ((idx / ntn) % ntk) * 64;
      int g  = idx / (ntn * ntk);

      // read: 64 rows x 16 float4; r = tid>>3, 8 lanes x 2 iters per row
      {
        int r  = tid >> 3;
        int c4 = tid & 7;
        const float* s = src + (size_t)g * K * N + (size_t)(k0 + r) * N + n0;
        #pragma unroll
        for (int i = 0; i < 2; i++) {
          float4 v = *(const float4*)(s + (i * 8 + c4) * 4);
          *(float4*)(ldsf + r * 65 + (i * 8 + c4) * 4) = v;
        }
      }
      __syncthreads();

      // write: 512 frag-rows of 8 bf16; tid -> (kt 0..1, f 0..3, lane)
      {
        unsigned short* d = dst + (size_t)g * K * N;
        int lane = tid & 63;
        int f    = (tid >> 6) & 3;
        int kt   = tid >> 8;
        int kl   = kt * 32 + (lane >> 4) * 8;   // k_local base
        int nl   = f * 16 + (lane & 15);        // n_local
        union { u16x8 v; unsigned short u[8]; } pk;
        #pragma unroll
        for (int j = 0; j < 8; j++)
          pk.u[j] = f2bf(ldsf[(kl + j) * 65 + nl]);
        int ktg = (k0 >> 5) + kt;
        int fg  = (n0 >> 4) + f;
        *(u16x8*)(d + (((size_t)ktg * (N >> 4) + fg) * 64 + lane) * 8) = pk.v;
      }
    } else {
      // ---- sort unit: counting sort of 8192 gates (threads 0..255 carry
      // per-thread state; prefix phase uses all 8 waves, one expert each) ----
      unsigned int* lcnt_lo = (unsigned int*)smem;         // [256]
      unsigned int* lcnt_hi = lcnt_lo + 256;               // [256]
      int* pre   = (int*)(smem + 2048);                    // [NE][256] = 8KB
      int* cnt8  = (int*)(smem + 2048 + 8192);             // [8]
      int* offs8 = cnt8 + 8;                               // [8]

      unsigned int gp[8];   // 32 gates, byte-packed (valid for tid<256)
      if (tid < 256) {
        unsigned int clo = 0, chi = 0;
        #pragma unroll
        for (int i = 0; i < 32; i++) {
          int g = clampe(gate[tid * 32 + i]);
          if ((i & 3) == 0) gp[i >> 2] = 0;
          gp[i >> 2] |= (unsigned int)g << (8 * (i & 3));
          if (g < 4) clo += 1u << (8 * g);
          else       chi += 1u << (8 * (g - 4));
        }
        lcnt_lo[tid] = clo;
        lcnt_hi[tid] = chi;
      }
      __syncthreads();

      {
        int wave = tid >> 6, lane = tid & 63;
        int e = wave;               // 8 waves -> 8 experts, single pass
        int carry = 0;
        #pragma unroll
        for (int ch = 0; ch < 4; ch++) {
          int idx = ch * 64 + lane;
          unsigned int word = (e < 4) ? lcnt_lo[idx] : lcnt_hi[idx];
          int v = (int)((word >> (8 * (e & 3))) & 255u);
          int s = v;
          #pragma unroll
          for (int d = 1; d < 64; d <<= 1) {
            int up = __shfl_up(s, d, 64);
            if (lane >= d) s += up;
          }
          pre[e * 256 + idx] = carry + s - v;   // exclusive prefix
          carry += __shfl(s, 63, 64);
        }
        if (lane == 0) cnt8[e] = carry;
      }
      __syncthreads();

      if (tid == 0) {
        int off = 0;
        for (int e = 0; e < NE; e++) {
          int cc = cnt8[e];
          meta[e] = cc;
          meta[8 + e] = off;
          offs8[e] = off;
          meta[16 + e] = (cc + BM3 - 1) / BM3;   // ntiles per expert
          off += cc;
        }
      }
      __syncthreads();

      if (tid < 256) {
        unsigned int rlo = 0, rhi = 0;
        #pragma unroll
        for (int i = 0; i < 32; i++) {
          int g = (int)((gp[i >> 2] >> (8 * (i & 3))) & 255u);
          int r;
          if (g < 4) { r = (int)((rlo >> (8 * g)) & 255u);       rlo += 1u << (8 * g); }
          else       { r = (int)((rhi >> (8 * (g - 4))) & 255u); rhi += 1u << (8 * (g - 4)); }
          perm[offs8[g] + pre[g * 256 + tid] + r] = tid * 32 + i;
        }
      }
    }
    __syncthreads();   // LDS reused by next unit / phase 2
  }

  // ================= grid barrier =================
  __threadfence();          // device-scope release of w*f / meta / perm
  cg::this_grid().sync();

  // ================= phase 2: fused 3-layer MLP (R3 structure) =================
  // deterministic tile assignment: block bid -> (expert e, tile trow)
  int e = -1, trow = 0;
  {
    int acc = 0;
    #pragma unroll
    for (int ee = 0; ee < NE; ee++) {
      int ntl = meta[16 + ee];
      if (e < 0 && bid < acc + ntl) { e = ee; trow = bid - acc; }
      acc += ntl;
    }
  }
  if (e < 0) return;                 // no tile for this block

  int cnt  = meta[e];
  int off  = meta[8 + e];
  int row0 = trow * BM3;

  if (tid < BM3) {
    int grow = row0 + tid;
    permc[tid] = (grow < cnt) ? perm[off + grow] : 0;
  }
  __syncthreads();

  int wave = tid >> 6, lane = tid & 63;
  int lm = lane & 15, quad = lane >> 4;

  // ---- gather h-tile: 48 rows x 512 fp32 -> bf16 sA[48][520] ----
  {
    int rr0 = tid >> 4;            // 0..31
    int cb  = (tid & 15) * 8;      // 0..120
    for (int r = rr0; r < BM3; r += 32) {
      const float* hrow = h + (size_t)permc[r] * ND;
      #pragma unroll
      for (int jj = 0; jj < 4; jj++) {
        int col = cb + jj * 128;
        float4 f0 = *(const float4*)(hrow + col);
        float4 f1 = *(const float4*)(hrow + col + 4);
        union { u16x8 v; unsigned short u[8]; } pk;
        pk.u[0] = f2bf(f0.x); pk.u[1] = f2bf(f0.y); pk.u[2] = f2bf(f0.z); pk.u[3] = f2bf(f0.w);
        pk.u[4] = f2bf(f1.x); pk.u[5] = f2bf(f1.y); pk.u[6] = f2bf(f1.z); pk.u[7] = f2bf(f1.w);
        *(u16x8*)(sA + r * 520 + col) = pk.v;
      }
    }
  }
  __syncthreads();

  f32x4 zero = {0.f, 0.f, 0.f, 0.f};

  // ---- Layer 1: sB = leaky(h x W1 + b1); wave n-slice 64; depth-1 pipeline ----
  {
    f32x4 acc[3][4];
    #pragma unroll
    for (int mi = 0; mi < 3; mi++)
      #pragma unroll
      for (int ni = 0; ni < 4; ni++)
        acc[mi][ni] = zero;
    const unsigned short* Wb = w1f + (size_t)e * ND * NH1 + ((size_t)(wave * 4) * 64 + lane) * 8;
    bf16x8 cur[4], nxt[4];
    #pragma unroll
    for (int ni = 0; ni < 4; ni++)
      cur[ni] = *reinterpret_cast<const bf16x8*>(Wb + ni * 512);
    for (int t = 0; t < 16; t++) {
      int tn = (t + 1 < 16) ? t + 1 : t;
      #pragma unroll
      for (int ni = 0; ni < 4; ni++)
        nxt[ni] = *reinterpret_cast<const bf16x8*>(Wb + (size_t)tn * 16384 + ni * 512);
      bf16x8 af[3];
      #pragma unroll
      for (int mi = 0; mi < 3; mi++)
        af[mi] = *reinterpret_cast<const bf16x8*>(sA + (mi * 16 + lm) * 520 + t * 32 + quad * 8);
      #pragma unroll
      for (int mi = 0; mi < 3; mi++)
        #pragma unroll
        for (int ni = 0; ni < 4; ni++)
          acc[mi][ni] = __builtin_amdgcn_mfma_f32_16x16x32_bf16(af[mi], cur[ni], acc[mi][ni], 0, 0, 0);
      #pragma unroll
      for (int ni = 0; ni < 4; ni++)
        cur[ni] = nxt[ni];
    }
    #pragma unroll
    for (int mi = 0; mi < 3; mi++)
      #pragma unroll
      for (int ni = 0; ni < 4; ni++) {
        int col = (wave * 4 + ni) * 16 + lm;
        float bv = b1[e * NH1 + col];
        #pragma unroll
        for (int r = 0; r < 4; r++) {
          int row = mi * 16 + quad * 4 + r;
          float v = acc[mi][ni][r] + bv;
          v = (v > 0.f) ? v : 0.2f * v;
          sB[row * 520 + col] = f2bf(v);
        }
      }
  }
  __syncthreads();   // sB ready; all L1 reads of sA done

  // ---- Layer 2: a2 (overlay sA, stride 264) = leaky(a1 x W2 + b2); n-slice 32 ----
  {
    f32x4 acc[3][2];
    #pragma unroll
    for (int mi = 0; mi < 3; mi++)
      #pragma unroll
      for (int ni = 0; ni < 2; ni++)
        acc[mi][ni] = zero;
    const unsigned short* Wb = w2f + (size_t)e * NH1 * NH2 + ((size_t)(wave * 2) * 64 + lane) * 8;
    bf16x8 cur[2], nxt[2];
    #pragma unroll
    for (int ni = 0; ni < 2; ni++)
      cur[ni] = *reinterpret_cast<const bf16x8*>(Wb + ni * 512);
    for (int t = 0; t < 16; t++) {
      int tn = (t + 1 < 16) ? t + 1 : t;
      #pragma unroll
      for (int ni = 0; ni < 2; ni++)
        nxt[ni] = *reinterpret_cast<const bf16x8*>(Wb + (size_t)tn * 8192 + ni * 512);
      bf16x8 af[3];
      #pragma unroll
      for (int mi = 0; mi < 3; mi++)
        af[mi] = *reinterpret_cast<const bf16x8*>(sB + (mi * 16 + lm) * 520 + t * 32 + quad * 8);
      #pragma unroll
      for (int mi = 0; mi < 3; mi++)
        #pragma unroll
        for (int ni = 0; ni < 2; ni++)
          acc[mi][ni] = __builtin_amdgcn_mfma_f32_16x16x32_bf16(af[mi], cur[ni], acc[mi][ni], 0, 0, 0);
      #pragma unroll
      for (int ni = 0; ni < 2; ni++)
        cur[ni] = nxt[ni];
    }
    #pragma unroll
    for (int mi = 0; mi < 3; mi++)
      #pragma unroll
      for (int ni = 0; ni < 2; ni++) {
        int col = (wave * 2 + ni) * 16 + lm;
        float bv = b2[e * NH2 + col];
        #pragma unroll
        for (int r = 0; r < 4; r++) {
          int row = mi * 16 + quad * 4 + r;
          float v = acc[mi][ni][r] + bv;
          v = (v > 0.f) ? v : 0.2f * v;
          sA[row * 264 + col] = f2bf(v);   // safe: L1 reads of sA complete
        }
      }
  }
  __syncthreads();   // a2 ready

  // ---- Layer 3: out = a2 x W3 + b3 (nt scatter); n-slice 32 ----
  {
    f32x4 acc[3][2];
    #pragma unroll
    for (int mi = 0; mi < 3; mi++)
      #pragma unroll
      for (int ni = 0; ni < 2; ni++)
        acc[mi][ni] = zero;
    const unsigned short* Wb = w3f + (size_t)e * NH2 * NY + ((size_t)(wave * 2) * 64 + lane) * 8;
    bf16x8 cur[2], nxt[2];
    #pragma unroll
    for (int ni = 0; ni < 2; ni++)
      cur[ni] = *reinterpret_cast<const bf16x8*>(Wb + ni * 512);
    for (int t = 0; t < 8; t++) {
      int tn = (t + 1 < 8) ? t + 1 : t;
      #pragma unroll
      for (int ni = 0; ni < 2; ni++)
        nxt[ni] = *reinterpret_cast<const bf16x8*>(Wb + (size_t)tn * 8192 + ni * 512);
      bf16x8 af[3];
      #pragma unroll
      for (int mi = 0; mi < 3; mi++)
        af[mi] = *reinterpret_cast<const bf16x8*>(sA + (mi * 16 + lm) * 264 + t * 32 + quad * 8);
      #pragma unroll
      for (int mi = 0; mi < 3; mi++)
        #pragma unroll
        for (int ni = 0; ni < 2; ni++)
          acc[mi][ni] = __builtin_amdgcn_mfma_f32_16x16x32_bf16(af[mi], cur[ni], acc[mi][ni], 0, 0, 0);
      #pragma unroll
      for (int ni = 0; ni < 2; ni++)
        cur[ni] = nxt[ni];
    }
    #pragma unroll
    for (int mi = 0; mi < 3; mi++)
      #pragma unroll
      for (int ni = 0; ni < 2; ni++) {
        int col = (wave * 2 + ni) * 16 + lm;
        float bv = b3[e * NY + col];
        #pragma unroll
        for (int r = 0; r < 4; r++) {
          int row = mi * 16 + quad * 4 + r;
          int grow = row0 + row;
          if (grow < cnt) {
            float v = acc[mi][ni][r] + bv;
            __builtin_nontemporal_store(v, &out[(size_t)permc[row] * NY + col]);
          }
        }
      }
  }
}

extern "C" void kernel_launch(void* const* d_in, const int* in_sizes, int n_in,
                              void* d_out, int out_size, void* d_ws, size_t ws_size,
                              hipStream_t stream) {
  (void)in_sizes; (void)n_in; (void)out_size; (void)ws_size;
  const float* h  = (const float*)d_in[0];
  const int* gate = (const int*)d_in[1];
  const float* W1 = (const float*)d_in[2];
  const float* b1 = (const float*)d_in[3];
  const float* W2 = (const float*)d_in[4];
  const float* b2 = (const float*)d_in[5];
  const float* W3 = (const float*)d_in[6];
  const float* b3 = (const float*)d_in[7];
  float* out = (float*)d_out;

  char* ws = (char*)d_ws;
  int* meta = (int*)ws;                               // 8 KB
  int* perm = (int*)(ws + 8192);                      // 32 KB
  unsigned short* w1f = (unsigned short*)(ws + 8192 + 32768);
  unsigned short* w2f = w1f + (size_t)NE * ND * NH1;
  unsigned short* w3f = w2f + (size_t)NE * NH1 * NH2;
  // ws total ~7.2 MB

  void* args[] = {
    (void*)&h, (void*)&gate, (void*)&W1, (void*)&W2, (void*)&W3,
    (void*)&b1, (void*)&b2, (void*)&b3, (void*)&out,
    (void*)&meta, (void*)&perm, (void*)&w1f, (void*)&w2f, (void*)&w3f
  };
  hipLaunchCooperativeKernel((const void*)moe_k, dim3(NBLK), dim3(512),
                             args, 0, stream);
}

// Round 5
// 113.079 us; speedup vs baseline: 1.7197x; 1.7197x over previous
//
#include <hip/hip_runtime.h>
#include <stdint.h>

#define NE 8
#define ND 512
#define NH1 512
#define NH2 256
#define NY 256
#define NB 8192
#define BM3 48                   /* fused-tile rows: <=178 tiles, one round on 256 CUs */
#define NBPE 24                  /* primary slots per expert; 8*24=192 */
#define NBLK (NE * NBPE)         /* 192 */
/* 64x64 transpose tiles */
#define W1T64 (NE * (ND/64) * (NH1/64))   /* 512 */
#define W2T64 (NE * (NH1/64) * (NH2/64))  /* 256 */
#define W3T64 (NE * (NH2/64) * (NY/64))   /* 128 */
#define WTT64 (W1T64 + W2T64 + W3T64)     /* 896 */

typedef float f32x4 __attribute__((ext_vector_type(4)));
typedef __bf16 bf16x8 __attribute__((ext_vector_type(8)));
typedef unsigned short u16x8 __attribute__((ext_vector_type(8)));

__device__ __forceinline__ unsigned short f2bf(float f) {
  unsigned int u = __float_as_uint(f);
  u += 0x7fffu + ((u >> 16) & 1u);   // round-to-nearest-even
  return (unsigned short)(u >> 16);
}

__device__ __forceinline__ int clampe(int g) {
  return g < 0 ? 0 : (g > NE - 1 ? NE - 1 : g);
}

// Fragment-order W layout: element (k = kt*32 + (lane>>4)*8 + j, n = f*16 + (lane&15))
// lives at Wf[(((kt * (N/16)) + f) * 64 + lane) * 8 + j]. One wave-load of frag
// (kt,f) = 64 lanes x 16B = 1KB fully contiguous.

// meta ints: [0..7] counts, [8..15] offs, [16..23] ntiles

// prep_k: 256 thr/block. Blocks 0..895: 64x64 W transpose tiles (float4 in,
// 16B frag-order out). Block 896: deterministic counting sort, 32 rows/thread.
__global__ __launch_bounds__(256)
void prep_k(const int* __restrict__ gate,
            const float* __restrict__ W1, const float* __restrict__ W2,
            const float* __restrict__ W3,
            unsigned short* __restrict__ w1f, unsigned short* __restrict__ w2f,
            unsigned short* __restrict__ w3f,
            int* __restrict__ meta, int* __restrict__ perm)
{
  __shared__ char sm[17024] __attribute__((aligned(16)));
  int b = blockIdx.x, t = threadIdx.x;

  if (b < WTT64) {
    float* ldsf = (float*)sm;   // [64][65]
    const float* src; unsigned short* dst; int K, N, idx;
    if (b < W1T64)          { src = W1; dst = w1f; K = ND;  N = NH1; idx = b; }
    else if (b < W1T64 + W2T64) { src = W2; dst = w2f; K = NH1; N = NH2; idx = b - W1T64; }
    else                    { src = W3; dst = w3f; K = NH2; N = NY;  idx = b - W1T64 - W2T64; }
    int ntn = N >> 6, ntk = K >> 6;
    int n0 = (idx % ntn) * 64;
    int k0 = ((idx / ntn) % ntk) * 64;
    int g  = idx / (ntn * ntk);

    // read: 64 rows x 16 float4; r = t>>2, 4 lanes x 4 iters per row
    {
      int r  = t >> 2;
      int c4 = t & 3;
      const float* s = src + (size_t)g * K * N + (size_t)(k0 + r) * N + n0;
      #pragma unroll
      for (int i = 0; i < 4; i++) {
        float4 v = *(const float4*)(s + (i * 4 + c4) * 4);
        *(float4*)(ldsf + r * 65 + (i * 4 + c4) * 4) = v;
      }
    }
    __syncthreads();

    // write: 512 frag-rows of 8 bf16; idx -> (kt 0..1, f 0..3, lane)
    unsigned short* d = dst + (size_t)g * K * N;
    #pragma unroll
    for (int ii = 0; ii < 2; ii++) {
      int idx2 = ii * 256 + t;
      int lane = idx2 & 63;
      int f    = (idx2 >> 6) & 3;
      int kt   = idx2 >> 8;
      int kl   = kt * 32 + (lane >> 4) * 8;   // k_local base
      int nl   = f * 16 + (lane & 15);        // n_local
      union { u16x8 v; unsigned short u[8]; } pk;
      #pragma unroll
      for (int j = 0; j < 8; j++)
        pk.u[j] = f2bf(ldsf[(kl + j) * 65 + nl]);
      int ktg = (k0 >> 5) + kt;
      int fg  = (n0 >> 4) + f;
      *(u16x8*)(d + (((size_t)ktg * (N >> 4) + fg) * 64 + lane) * 8) = pk.v;
    }
    return;
  }

  // ---- sort block: 256 threads x 32 rows each (deterministic, no global atomics) ----
  unsigned int* lcnt_lo = (unsigned int*)sm;           // [256]
  unsigned int* lcnt_hi = lcnt_lo + 256;               // [256]
  int* pre   = (int*)(sm + 2048);                      // [NE][256] = 8KB
  int* cnt8  = (int*)(sm + 2048 + 8192);               // [8]
  int* offs8 = cnt8 + 8;                               // [8]

  unsigned int gp[8];   // 32 gates, byte-packed
  unsigned int clo = 0, chi = 0;
  #pragma unroll
  for (int i = 0; i < 32; i++) {
    int g = clampe(gate[t * 32 + i]);
    if ((i & 3) == 0) gp[i >> 2] = 0;
    gp[i >> 2] |= (unsigned int)g << (8 * (i & 3));
    if (g < 4) clo += 1u << (8 * g);
    else       chi += 1u << (8 * (g - 4));
  }
  lcnt_lo[t] = clo;
  lcnt_hi[t] = chi;
  __syncthreads();

  int wave = t >> 6, lane = t & 63;
  #pragma unroll
  for (int pass = 0; pass < 2; pass++) {
    int e = wave + pass * 4;
    int carry = 0;
    #pragma unroll
    for (int ch = 0; ch < 4; ch++) {
      int idx = ch * 64 + lane;
      unsigned int word = (e < 4) ? lcnt_lo[idx] : lcnt_hi[idx];
      int v = (int)((word >> (8 * (e & 3))) & 255u);
      int s = v;
      #pragma unroll
      for (int d = 1; d < 64; d <<= 1) {
        int up = __shfl_up(s, d, 64);
        if (lane >= d) s += up;
      }
      pre[e * 256 + idx] = carry + s - v;   // exclusive prefix
      carry += __shfl(s, 63, 64);
    }
    if (lane == 0) cnt8[e] = carry;
  }
  __syncthreads();

  if (t == 0) {
    int off = 0;
    for (int e = 0; e < NE; e++) {
      int cc = cnt8[e];
      meta[e] = cc;
      meta[8 + e] = off;
      offs8[e] = off;
      meta[16 + e] = (cc + BM3 - 1) / BM3;   // ntiles per expert
      off += cc;
    }
  }
  __syncthreads();

  unsigned int rlo = 0, rhi = 0;
  #pragma unroll
  for (int i = 0; i < 32; i++) {
    int g = (int)((gp[i >> 2] >> (8 * (i & 3))) & 255u);
    int r;
    if (g < 4) { r = (int)((rlo >> (8 * g)) & 255u);       rlo += 1u << (8 * g); }
    else       { r = (int)((rhi >> (8 * (g - 4))) & 255u); rhi += 1u << (8 * (g - 4)); }
    perm[offs8[g] + pre[g * 256 + t] + r] = t * 32 + i;
  }
}

// Fused 3-layer MLP per 48-row tile (R3 champion structure).
// This round's single change: the per-block tile claim (device atomicAdd on one
// contended line + s_getreg, serialized across ~190 blocks at startup) is
// replaced by a zero-atomic static inverse map: primary slot bid = e + 8*j
// -> tile j of expert e, which keeps expert<->XCD alignment under round-robin
// dispatch; skew overflow (ntiles > 24) is rank-matched onto free slots
// deterministically (bijective for any gate distribution: free >= overflow).
__global__ __launch_bounds__(512, 4)
void mlp_k(const float* __restrict__ h,
           const float* __restrict__ b1, const float* __restrict__ b2,
           const float* __restrict__ b3,
           float* __restrict__ out,
           const int* __restrict__ meta, const int* __restrict__ perm,
           const unsigned short* __restrict__ w1f,
           const unsigned short* __restrict__ w2f,
           const unsigned short* __restrict__ w3f)
{
  __shared__ unsigned short sA[BM3 * 520];   // h-tile (stride 520); a2 overlays (stride 264)
  __shared__ unsigned short sB[BM3 * 520];   // a1 (stride 520)
  __shared__ int permc[BM3];

  int bid = blockIdx.x, tid = threadIdx.x;

  // ---- static tile map: bid -> (expert e, tile trow) ----
  int ntl[NE];
  #pragma unroll
  for (int ee = 0; ee < NE; ee++) ntl[ee] = meta[16 + ee];

  int e = -1, trow = 0;
  {
    int e0 = bid & 7, j0 = bid >> 3;
    int cap0 = ntl[e0] < NBPE ? ntl[e0] : NBPE;
    if (j0 < cap0) {
      e = e0; trow = j0;                    // primary slot (common path)
    } else {
      // free-slot rank of bid = #free slots strictly below bid
      int r = 0;
      #pragma unroll
      for (int ee = 0; ee < NE; ee++) {
        int capv = ntl[ee] < NBPE ? ntl[ee] : NBPE;
        int nj = bid > ee ? ((bid - ee + 7) >> 3) : 0;   // slots ee+8j < bid
        if (nj > NBPE) nj = NBPE;
        int fr = nj - capv;
        if (fr > 0) r += fr;
      }
      // overflow tile with rank r
      int acc = 0;
      #pragma unroll
      for (int ee = 0; ee < NE; ee++) {
        int ov = ntl[ee] - NBPE;
        if (ov < 0) ov = 0;
        if (e < 0 && r < acc + ov) { e = ee; trow = NBPE + (r - acc); }
        acc += ov;
      }
    }
  }
  if (e < 0) return;                 // idle slot

  int cnt  = meta[e];
  int off  = meta[8 + e];
  int row0 = trow * BM3;

  if (tid < BM3) {
    int grow = row0 + tid;
    permc[tid] = (grow < cnt) ? perm[off + grow] : 0;
  }
  __syncthreads();

  int wave = tid >> 6, lane = tid & 63;
  int lm = lane & 15, quad = lane >> 4;

  // ---- gather h-tile: 48 rows x 512 fp32 -> bf16 sA[48][520] ----
  {
    int rr0 = tid >> 4;            // 0..31
    int cb  = (tid & 15) * 8;      // 0..120
    for (int r = rr0; r < BM3; r += 32) {
      const float* hrow = h + (size_t)permc[r] * ND;
      #pragma unroll
      for (int jj = 0; jj < 4; jj++) {
        int col = cb + jj * 128;
        float4 f0 = *(const float4*)(hrow + col);
        float4 f1 = *(const float4*)(hrow + col + 4);
        union { u16x8 v; unsigned short u[8]; } pk;
        pk.u[0] = f2bf(f0.x); pk.u[1] = f2bf(f0.y); pk.u[2] = f2bf(f0.z); pk.u[3] = f2bf(f0.w);
        pk.u[4] = f2bf(f1.x); pk.u[5] = f2bf(f1.y); pk.u[6] = f2bf(f1.z); pk.u[7] = f2bf(f1.w);
        *(u16x8*)(sA + r * 520 + col) = pk.v;
      }
    }
  }
  __syncthreads();

  f32x4 zero = {0.f, 0.f, 0.f, 0.f};

  // ---- Layer 1: sB = leaky(h x W1 + b1); wave n-slice 64; depth-1 pipeline ----
  {
    f32x4 acc[3][4];
    #pragma unroll
    for (int mi = 0; mi < 3; mi++)
      #pragma unroll
      for (int ni = 0; ni < 4; ni++)
        acc[mi][ni] = zero;
    const unsigned short* Wb = w1f + (size_t)e * ND * NH1 + ((size_t)(wave * 4) * 64 + lane) * 8;
    bf16x8 cur[4], nxt[4];
    #pragma unroll
    for (int ni = 0; ni < 4; ni++)
      cur[ni] = *reinterpret_cast<const bf16x8*>(Wb + ni * 512);
    for (int t = 0; t < 16; t++) {
      int tn = (t + 1 < 16) ? t + 1 : t;
      #pragma unroll
      for (int ni = 0; ni < 4; ni++)
        nxt[ni] = *reinterpret_cast<const bf16x8*>(Wb + (size_t)tn * 16384 + ni * 512);
      bf16x8 af[3];
      #pragma unroll
      for (int mi = 0; mi < 3; mi++)
        af[mi] = *reinterpret_cast<const bf16x8*>(sA + (mi * 16 + lm) * 520 + t * 32 + quad * 8);
      #pragma unroll
      for (int mi = 0; mi < 3; mi++)
        #pragma unroll
        for (int ni = 0; ni < 4; ni++)
          acc[mi][ni] = __builtin_amdgcn_mfma_f32_16x16x32_bf16(af[mi], cur[ni], acc[mi][ni], 0, 0, 0);
      #pragma unroll
      for (int ni = 0; ni < 4; ni++)
        cur[ni] = nxt[ni];
    }
    #pragma unroll
    for (int mi = 0; mi < 3; mi++)
      #pragma unroll
      for (int ni = 0; ni < 4; ni++) {
        int col = (wave * 4 + ni) * 16 + lm;
        float bv = b1[e * NH1 + col];
        #pragma unroll
        for (int r = 0; r < 4; r++) {
          int row = mi * 16 + quad * 4 + r;
          float v = acc[mi][ni][r] + bv;
          v = (v > 0.f) ? v : 0.2f * v;
          sB[row * 520 + col] = f2bf(v);
        }
      }
  }
  __syncthreads();   // sB ready; all L1 reads of sA done

  // ---- Layer 2: a2 (overlay sA, stride 264) = leaky(a1 x W2 + b2); n-slice 32 ----
  {
    f32x4 acc[3][2];
    #pragma unroll
    for (int mi = 0; mi < 3; mi++)
      #pragma unroll
      for (int ni = 0; ni < 2; ni++)
        acc[mi][ni] = zero;
    const unsigned short* Wb = w2f + (size_t)e * NH1 * NH2 + ((size_t)(wave * 2) * 64 + lane) * 8;
    bf16x8 cur[2], nxt[2];
    #pragma unroll
    for (int ni = 0; ni < 2; ni++)
      cur[ni] = *reinterpret_cast<const bf16x8*>(Wb + ni * 512);
    for (int t = 0; t < 16; t++) {
      int tn = (t + 1 < 16) ? t + 1 : t;
      #pragma unroll
      for (int ni = 0; ni < 2; ni++)
        nxt[ni] = *reinterpret_cast<const bf16x8*>(Wb + (size_t)tn * 8192 + ni * 512);
      bf16x8 af[3];
      #pragma unroll
      for (int mi = 0; mi < 3; mi++)
        af[mi] = *reinterpret_cast<const bf16x8*>(sB + (mi * 16 + lm) * 520 + t * 32 + quad * 8);
      #pragma unroll
      for (int mi = 0; mi < 3; mi++)
        #pragma unroll
        for (int ni = 0; ni < 2; ni++)
          acc[mi][ni] = __builtin_amdgcn_mfma_f32_16x16x32_bf16(af[mi], cur[ni], acc[mi][ni], 0, 0, 0);
      #pragma unroll
      for (int ni = 0; ni < 2; ni++)
        cur[ni] = nxt[ni];
    }
    #pragma unroll
    for (int mi = 0; mi < 3; mi++)
      #pragma unroll
      for (int ni = 0; ni < 2; ni++) {
        int col = (wave * 2 + ni) * 16 + lm;
        float bv = b2[e * NH2 + col];
        #pragma unroll
        for (int r = 0; r < 4; r++) {
          int row = mi * 16 + quad * 4 + r;
          float v = acc[mi][ni][r] + bv;
          v = (v > 0.f) ? v : 0.2f * v;
          sA[row * 264 + col] = f2bf(v);   // safe: L1 reads of sA complete
        }
      }
  }
  __syncthreads();   // a2 ready

  // ---- Layer 3: out = a2 x W3 + b3 (nt scatter); n-slice 32 ----
  {
    f32x4 acc[3][2];
    #pragma unroll
    for (int mi = 0; mi < 3; mi++)
      #pragma unroll
      for (int ni = 0; ni < 2; ni++)
        acc[mi][ni] = zero;
    const unsigned short* Wb = w3f + (size_t)e * NH2 * NY + ((size_t)(wave * 2) * 64 + lane) * 8;
    bf16x8 cur[2], nxt[2];
    #pragma unroll
    for (int ni = 0; ni < 2; ni++)
      cur[ni] = *reinterpret_cast<const bf16x8*>(Wb + ni * 512);
    for (int t = 0; t < 8; t++) {
      int tn = (t + 1 < 8) ? t + 1 : t;
      #pragma unroll
      for (int ni = 0; ni < 2; ni++)
        nxt[ni] = *reinterpret_cast<const bf16x8*>(Wb + (size_t)tn * 8192 + ni * 512);
      bf16x8 af[3];
      #pragma unroll
      for (int mi = 0; mi < 3; mi++)
        af[mi] = *reinterpret_cast<const bf16x8*>(sA + (mi * 16 + lm) * 264 + t * 32 + quad * 8);
      #pragma unroll
      for (int mi = 0; mi < 3; mi++)
        #pragma unroll
        for (int ni = 0; ni < 2; ni++)
          acc[mi][ni] = __builtin_amdgcn_mfma_f32_16x16x32_bf16(af[mi], cur[ni], acc[mi][ni], 0, 0, 0);
      #pragma unroll
      for (int ni = 0; ni < 2; ni++)
        cur[ni] = nxt[ni];
    }
    #pragma unroll
    for (int mi = 0; mi < 3; mi++)
      #pragma unroll
      for (int ni = 0; ni < 2; ni++) {
        int col = (wave * 2 + ni) * 16 + lm;
        float bv = b3[e * NY + col];
        #pragma unroll
        for (int r = 0; r < 4; r++) {
          int row = mi * 16 + quad * 4 + r;
          int grow = row0 + row;
          if (grow < cnt) {
            float v = acc[mi][ni][r] + bv;
            __builtin_nontemporal_store(v, &out[(size_t)permc[row] * NY + col]);
          }
        }
      }
  }
}

extern "C" void kernel_launch(void* const* d_in, const int* in_sizes, int n_in,
                              void* d_out, int out_size, void* d_ws, size_t ws_size,
                              hipStream_t stream) {
  (void)in_sizes; (void)n_in; (void)out_size; (void)ws_size;
  const float* h  = (const float*)d_in[0];
  const int* gate = (const int*)d_in[1];
  const float* W1 = (const float*)d_in[2];
  const float* b1 = (const float*)d_in[3];
  const float* W2 = (const float*)d_in[4];
  const float* b2 = (const float*)d_in[5];
  const float* W3 = (const float*)d_in[6];
  const float* b3 = (const float*)d_in[7];
  float* out = (float*)d_out;

  char* ws = (char*)d_ws;
  int* meta = (int*)ws;                               // 8 KB
  int* perm = (int*)(ws + 8192);                      // 32 KB
  unsigned short* w1f = (unsigned short*)(ws + 8192 + 32768);
  unsigned short* w2f = w1f + (size_t)NE * ND * NH1;
  unsigned short* w3f = w2f + (size_t)NE * NH1 * NH2;
  // ws total ~7.2 MB

  prep_k<<<WTT64 + 1, 256, 0, stream>>>(gate, W1, W2, W3, w1f, w2f, w3f, meta, perm);
  mlp_k<<<NBLK, 512, 0, stream>>>(h, b1, b2, b3, out, meta, perm, w1f, w2f, w3f);
}